// Round 8
// baseline (133.431 us; speedup 1.0000x reference)
//
#include <hip/hip_runtime.h>
#include <hip/hip_fp16.h>

#define N_NODES 100000
#define E_EDGES 1600000
#define IN_C 128
#define HID_C 64
#define OUT_C 32
#define BNODES 64                                   // nodes per bucket (dst>>6)
#define NBUCK ((N_NODES + BNODES - 1) / BNODES)     // 1563
#define MAXB 2048                                   // bucket cap (mean 1024, sigma~32)
#define NCHUNK 256                                  // edge chunks (privatized hist)
#define CHUNK_E (E_EDGES / NCHUNK)                  // 6250

// chunk<->block swizzle: consecutive chunks land on the same XCD (blockIdx%8 heuristic),
// so adjacent bucket windows (shared 64B lines) merge in one L2 instead of ping-ponging.
__device__ __forceinline__ int chunk_of_block(int b) { return (b & 7) * (NCHUNK / 8) + (b >> 3); }

// ---- zero the global bucket cursors (workspace is poisoned between iterations) ----
__global__ void zero_gcur_kernel(int* __restrict__ gcur) {
    int i = blockIdx.x * 256 + threadIdx.x;
    if (i < NBUCK) gcur[i] = 0;
}

// ---- single-pass bucketing: per-chunk LDS histogram -> atomic window reservation in
//      gcur -> scatter into PADDED per-bucket regions (b*MAXB). ----
__global__ __launch_bounds__(1024) void bucket_scatter_kernel(const int* __restrict__ src,
                                                              const int* __restrict__ dst,
                                                              int* __restrict__ gcur,
                                                              unsigned* __restrict__ pairs) {
    __shared__ int h[NBUCK];                        // count -> base cursor (reused)
    for (int i = threadIdx.x; i < NBUCK; i += 1024) h[i] = 0;
    __syncthreads();
    const int chunk = chunk_of_block(blockIdx.x);
    const int base = chunk * CHUNK_E;
    int dc[7];                                      // ceil(6250/1024) = 7
    int nj = 0;
    for (int j = threadIdx.x; j < CHUNK_E; j += 1024) {
        int d = dst[base + j];
        dc[nj++] = d;
        atomicAdd(&h[d >> 6], 1);
    }
    __syncthreads();
    for (int i = threadIdx.x; i < NBUCK; i += 1024) {
        int c = h[i];
        if (c > 0) h[i] = atomicAdd(&gcur[i], c);   // reserve window; h becomes cursor
    }
    __syncthreads();
    nj = 0;
    for (int j = threadIdx.x; j < CHUNK_E; j += 1024) {
        int d = dc[nj++];
        int pos = atomicAdd(&h[d >> 6], 1);
        pairs[(unsigned)(d >> 6) * MAXB + (unsigned)pos] =
            ((unsigned)src[base + j] << 6) | (unsigned)(d & 63);
    }
}

// ---- per-bucket counting sort -> node-level padded CSR, in place (LDS stage). ----
__global__ __launch_bounds__(256) void bucket_sort_kernel(const int* __restrict__ gcur,
                                                          unsigned* __restrict__ pairs,
                                                          int* __restrict__ row_beg,
                                                          int* __restrict__ row_end,
                                                          float* __restrict__ dinv) {
    __shared__ unsigned sp[MAXB];
    __shared__ int hcnt[BNODES], scn[BNODES], cur[BNODES];
    const int b = blockIdx.x;
    const int beg = b * MAXB;
    int cnt = gcur[b];
    if (cnt > MAXB) cnt = MAXB;                     // safety clamp (cap is 32 sigma)
    if (threadIdx.x < BNODES) hcnt[threadIdx.x] = 0;
    __syncthreads();
    for (int j = threadIdx.x; j < cnt; j += 256) {
        unsigned p = pairs[beg + j];
        sp[j] = p;
        atomicAdd(&hcnt[p & 63], 1);
    }
    __syncthreads();
    if (threadIdx.x < BNODES) scn[threadIdx.x] = hcnt[threadIdx.x];
    __syncthreads();
    for (int off = 1; off < BNODES; off <<= 1) {
        int t = 0;
        if (threadIdx.x < BNODES && threadIdx.x >= off) t = scn[threadIdx.x - off];
        __syncthreads();
        if (threadIdx.x < BNODES) scn[threadIdx.x] += t;
        __syncthreads();
    }
    if (threadIdx.x < BNODES) {
        int ex = scn[threadIdx.x] - hcnt[threadIdx.x];   // exclusive
        cur[threadIdx.x] = ex;
        int node = b * BNODES + threadIdx.x;
        if (node < N_NODES) {
            row_beg[node] = beg + ex;
            row_end[node] = beg + ex + hcnt[threadIdx.x];
            dinv[node] = rsqrtf((float)hcnt[threadIdx.x] + 1.0f);
        }
    }
    __syncthreads();
    for (int j = threadIdx.x; j < cnt; j += 256) {
        unsigned p = sp[j];
        int pos = atomicAdd(&cur[p & 63], 1);
        pairs[beg + pos] = p >> 6;                      // now plain src index
    }
}

// ---- hs(fp16) = dinv[row] * (x @ W1) : 2 rows x 8 cols per thread, 64 rows/block,
//      grid 1563. Same k-order per output element -> bit-identical hs. ----
__global__ __launch_bounds__(256) void gemm1_kernel(const float* __restrict__ x,
                                                    const float* __restrict__ W1,
                                                    const float* __restrict__ dinv,
                                                    __half* __restrict__ hs) {
    __shared__ float sW[IN_C * HID_C];
    for (int i = threadIdx.x; i < IN_C * HID_C; i += 256) sW[i] = W1[i];
    __syncthreads();
    const int cg = (threadIdx.x & 7) * 8;
    const int row0 = blockIdx.x * 64 + (threadIdx.x >> 3) * 2;
    float acc[2][8];
#pragma unroll
    for (int r = 0; r < 2; ++r)
#pragma unroll
        for (int c = 0; c < 8; ++c) acc[r][c] = 0.f;

    int rr[2];
#pragma unroll
    for (int r = 0; r < 2; ++r) rr[r] = min(row0 + r, N_NODES - 1);

    const float4* x4 = (const float4*)x;
#pragma unroll 2
    for (int k4 = 0; k4 < IN_C / 4; ++k4) {
        float4 xv[2];
#pragma unroll
        for (int r = 0; r < 2; ++r) xv[r] = x4[(size_t)rr[r] * (IN_C / 4) + k4];
        float xs[2][4];
#pragma unroll
        for (int r = 0; r < 2; ++r) {
            xs[r][0] = xv[r].x; xs[r][1] = xv[r].y; xs[r][2] = xv[r].z; xs[r][3] = xv[r].w;
        }
#pragma unroll
        for (int kk = 0; kk < 4; ++kk) {
            const float4* wp = (const float4*)(sW + (k4 * 4 + kk) * HID_C + cg);
            float4 w0 = wp[0], w1 = wp[1];
            float wv[8] = {w0.x, w0.y, w0.z, w0.w, w1.x, w1.y, w1.z, w1.w};
#pragma unroll
            for (int r = 0; r < 2; ++r)
#pragma unroll
                for (int c = 0; c < 8; ++c)
                    acc[r][c] = fmaf(xs[r][kk], wv[c], acc[r][c]);
        }
    }
#pragma unroll
    for (int r = 0; r < 2; ++r) {
        int row = row0 + r;
        if (row < N_NODES) {
            float dv = dinv[row];
            union { float4 f; __half2 h[4]; } u;
#pragma unroll
            for (int q = 0; q < 4; ++q)
                u.h[q] = __floats2half2_rn(acc[r][2 * q] * dv, acc[r][2 * q + 1] * dv);
            *(float4*)(hs + (size_t)row * HID_C + cg) = u.f;   // 16 B packed store
        }
    }
}

// gather/consume building blocks (static indexing only; ascending edge order)
#define AG_GATHER(V, CV, TBL, STRIDE)                                         \
    _Pragma("unroll")                                                         \
    for (int e = 0; e < 8; ++e) {                                             \
        int s_ = __shfl((CV), e, 8);                                          \
        (V)[e] = (TBL)[(unsigned)(s_ * (STRIDE) + lane)];                     \
    }
#define AG_CONSUME(V)                                                         \
    _Pragma("unroll")                                                         \
    for (int e = 0; e < 8; ++e) {                                             \
        __half2* vh_ = (__half2*)&(V)[e];                                     \
        float2 w0_ = __half22float2(vh_[0]), w1_ = __half22float2(vh_[1]);    \
        a0 += w0_.x; a1 += w0_.y; a2 += w1_.x; a3 += w1_.y;                   \
    }

// ---- layer-1 aggregate + FUSED gemm2.  16 lanes x float2 per node (4 nodes/wave).
//      Gather: 2-buffer (A/B) software pipeline — consume chunk c while c+1 is in
//      flight and c+2 is issuing (round-5 lesson: explicit buffers, not a predicated
//      mega-batch); tail (<8 edges) gathers issued in the prologue. Consume order is
//      ascending -> bit-identical sums. Epilogue: sh2 padded [16][33] (kills 4-way
//      nl bank conflict), sW read as conflict-free b64 (w[k][oc],w[k][oc+1] adjacent),
//      k ascending -> bit-identical gs. gs must NOT alias hs. ----
__global__ __launch_bounds__(256) void agg1_kernel(const int* __restrict__ row_beg,
                                                   const int* __restrict__ row_end,
                                                   const int* __restrict__ col,
                                                   const float2* __restrict__ hsf,
                                                   const float* __restrict__ dinv,
                                                   const float* __restrict__ b1,
                                                   const float* __restrict__ W2,
                                                   __half* __restrict__ gs) {
    __shared__ float sW[HID_C * OUT_C];            // 8 KB W2 copy, row-major [64][32]
    __shared__ __half2 sh2[16][HID_C / 2 + 1];     // padded h2 tile (conflict-free)
    for (int i = threadIdx.x; i < HID_C * OUT_C; i += 256) sW[i] = W2[i];

    const int nl = threadIdx.x >> 4;               // node slot in block (0..15)
    const int node = blockIdx.x * 16 + nl;         // grid 6250 * 16 = exactly N
    const int lane = threadIdx.x & 15;             // float2 index: channels 4*lane..4*lane+3
    const int beg = row_beg[node], end = row_end[node];
    const int deg = end - beg;
    const int F = deg >> 3;                        // full 8-edge chunks

    float2 u = hsf[(unsigned)(node * 16 + lane)];  // self loop
    __half2* uh = (__half2*)&u;
    float2 t0 = __half22float2(uh[0]), t1 = __half22float2(uh[1]);
    float a0 = t0.x, a1 = t0.y, a2 = t1.x, a3 = t1.y;

    float2 vA[8], vB[8], vT[8];
    int cvA = 0, cvB = 0, cvT = 0;
    if (F >= 1) { cvA = col[beg + (lane & 7)];     AG_GATHER(vA, cvA, hsf, 16); }
    if (F >= 2) { cvB = col[beg + 8 + (lane & 7)]; AG_GATHER(vB, cvB, hsf, 16); }
    {   // tail indices (guarded; OOB lanes gather row 0 -> valid, cached, discarded)
        int ti = beg + F * 8 + (lane & 7);
        cvT = (ti < end) ? col[ti] : 0;
        AG_GATHER(vT, cvT, hsf, 16);
    }
    int c = 0;
    while (c + 2 < F) {                            // A holds even chunks, B odd
        int cvN = col[beg + (c + 2) * 8 + (lane & 7)];
        AG_CONSUME(vA);
        AG_GATHER(vA, cvN, hsf, 16);
        ++c;
        if (c + 2 < F) {
            int cvN2 = col[beg + (c + 2) * 8 + (lane & 7)];
            AG_CONSUME(vB);
            AG_GATHER(vB, cvN2, hsf, 16);
            ++c;
        }
    }
    while (c < F) {                                // drain (<=2 iterations, parity-routed)
        if ((c & 1) == 0) { AG_CONSUME(vA); } else { AG_CONSUME(vB); }
        ++c;
    }
    const int tail = deg & 7;                      // predicated tail consume (static idx)
#pragma unroll
    for (int e = 0; e < 8; ++e) {
        if (e < tail) {
            __half2* vh = (__half2*)&vT[e];
            float2 w0 = __half22float2(vh[0]), w1 = __half22float2(vh[1]);
            a0 += w0.x; a1 += w0.y; a2 += w1.x; a3 += w1.y;
        }
    }

    const float dv = dinv[node];
    float4 bb = ((const float4*)b1)[lane];
    __half2 p0 = __floats2half2_rn(fmaxf(dv * a0 + bb.x, 0.f), fmaxf(dv * a1 + bb.y, 0.f));
    __half2 p1 = __floats2half2_rn(fmaxf(dv * a2 + bb.z, 0.f), fmaxf(dv * a3 + bb.w, 0.f));
    sh2[nl][lane * 2] = p0;
    sh2[nl][lane * 2 + 1] = p1;
    __syncthreads();                               // covers sW and sh2

    // gemm2 phase: thread -> (node nl, out channels oc, oc+1); k order 0..63 sequential.
    // w pair read as b64 (adjacent floats, banks {2j,2j+1} -> conflict-free).
    const int oc = lane * 2;
    const float2* wp2 = (const float2*)sW;         // w[k] pair at index k*16 + (oc>>1)
    float o0 = 0.f, o1 = 0.f;
#pragma unroll
    for (int k2 = 0; k2 < HID_C / 2; ++k2) {
        float2 hv = __half22float2(sh2[nl][k2]);
        float2 wa = wp2[(2 * k2) * (OUT_C / 2) + (oc >> 1)];
        float2 wb = wp2[(2 * k2 + 1) * (OUT_C / 2) + (oc >> 1)];
        o0 = fmaf(hv.x, wa.x, o0); o1 = fmaf(hv.x, wa.y, o1);
        o0 = fmaf(hv.y, wb.x, o0); o1 = fmaf(hv.y, wb.y, o1);
    }
    *(__half2*)(gs + (unsigned)(node * OUT_C + oc)) = __floats2half2_rn(o0 * dv, o1 * dv);
}

// ---- layer-2 aggregate: 8 lanes x float2 per node (8 nodes/wave), full 64 B rows,
//      same 2-buffer pipelined gather + prologue tail. ----
__global__ void agg2_kernel(const int* __restrict__ row_beg, const int* __restrict__ row_end,
                            const int* __restrict__ col,
                            const float2* __restrict__ gsf, const float* __restrict__ dinv,
                            const float* __restrict__ b2, float* __restrict__ out) {
    const int node = blockIdx.x * 32 + (threadIdx.x >> 3);   // grid 3125*32 == N exactly
    const int lane = threadIdx.x & 7;              // float2 index: channels 4*lane..4*lane+3
    const int beg = row_beg[node], end = row_end[node];
    const int deg = end - beg;
    const int F = deg >> 3;

    float2 u = gsf[(unsigned)(node * 8 + lane)];   // self loop
    __half2* uh = (__half2*)&u;
    float2 t0 = __half22float2(uh[0]), t1 = __half22float2(uh[1]);
    float a0 = t0.x, a1 = t0.y, a2 = t1.x, a3 = t1.y;

    float2 vA[8], vB[8], vT[8];
    int cvA = 0, cvB = 0, cvT = 0;
    if (F >= 1) { cvA = col[beg + lane];     AG_GATHER(vA, cvA, gsf, 8); }
    if (F >= 2) { cvB = col[beg + 8 + lane]; AG_GATHER(vB, cvB, gsf, 8); }
    {
        int ti = beg + F * 8 + lane;
        cvT = (ti < end) ? col[ti] : 0;
        AG_GATHER(vT, cvT, gsf, 8);
    }
    int c = 0;
    while (c + 2 < F) {
        int cvN = col[beg + (c + 2) * 8 + lane];
        AG_CONSUME(vA);
        AG_GATHER(vA, cvN, gsf, 8);
        ++c;
        if (c + 2 < F) {
            int cvN2 = col[beg + (c + 2) * 8 + lane];
            AG_CONSUME(vB);
            AG_GATHER(vB, cvN2, gsf, 8);
            ++c;
        }
    }
    while (c < F) {
        if ((c & 1) == 0) { AG_CONSUME(vA); } else { AG_CONSUME(vB); }
        ++c;
    }
    const int tail = deg & 7;
#pragma unroll
    for (int e = 0; e < 8; ++e) {
        if (e < tail) {
            __half2* vh = (__half2*)&vT[e];
            float2 w0 = __half22float2(vh[0]), w1 = __half22float2(vh[1]);
            a0 += w0.x; a1 += w0.y; a2 += w1.x; a3 += w1.y;
        }
    }
    float dv = dinv[node];
    float4 bb = ((const float4*)b2)[lane];
    float4 o;
    o.x = dv * a0 + bb.x;
    o.y = dv * a1 + bb.y;
    o.z = dv * a2 + bb.z;
    o.w = dv * a3 + bb.w;
    *(float4*)(out + (unsigned)(node * OUT_C + lane * 4)) = o;
}

extern "C" void kernel_launch(void* const* d_in, const int* in_sizes, int n_in,
                              void* d_out, int out_size, void* d_ws, size_t ws_size,
                              hipStream_t stream) {
    const float* x  = (const float*)d_in[0];   // [N,128]
    const int*   ei = (const int*)d_in[1];     // [2,E]
    const float* W1 = (const float*)d_in[2];   // [128,64]
    const float* b1 = (const float*)d_in[3];   // [64]
    const float* W2 = (const float*)d_in[4];   // [64,32]
    const float* b2 = (const float*)d_in[5];   // [32]
    float* out = (float*)d_out;                // [N,32]

    const int* srcv = ei;
    const int* dstv = ei + E_EDGES;

    // workspace layout (~33 MB; ws is ~268 MB). gs is a DEDICATED region (agg1 reads
    // hs while writing gs -> must not alias).
    float* dinv  = (float*)d_ws;                            // N floats
    __half* hs   = (__half*)(dinv + N_NODES);               // N*64 halves
    __half* gs   = hs + (size_t)N_NODES * HID_C;            // N*32 halves
    int* row_beg = (int*)(gs + (size_t)N_NODES * OUT_C);    // N
    int* row_end = row_beg + N_NODES;                       // N
    int* gcur    = row_end + N_NODES;                       // NBUCK (pad to 1568)
    unsigned* pairs = (unsigned*)(gcur + 1568);             // NBUCK*MAXB (padded buckets)
    int* col = (int*)pairs;

    // CSR build: atomic bucket-window reservation
    zero_gcur_kernel<<<(NBUCK + 255) / 256, 256, 0, stream>>>(gcur);
    bucket_scatter_kernel<<<NCHUNK, 1024, 0, stream>>>(srcv, dstv, gcur, pairs);
    bucket_sort_kernel<<<NBUCK, 256, 0, stream>>>(gcur, pairs, row_beg, row_end, dinv);

    // layer 1 GEMM (64 rows/block, grid 1563)
    gemm1_kernel<<<(N_NODES + 63) / 64, 256, 0, stream>>>(x, W1, dinv, hs);

    // layer-1 aggregate + fused layer-2 GEMM
    agg1_kernel<<<N_NODES / 16, 256, 0, stream>>>(row_beg, row_end, col,
                                                  (const float2*)hs, dinv, b1, W2, gs);

    // layer-2 aggregate
    agg2_kernel<<<(N_NODES + 31) / 32, 256, 0, stream>>>(row_beg, row_end, col,
                                                         (const float2*)gs, dinv, b2, out);
}